// Round 3
// baseline (1163.615 us; speedup 1.0000x reference)
//
#include <hip/hip_runtime.h>
#include <hip/hip_bf16.h>

typedef __bf16 bf16x8 __attribute__((ext_vector_type(8)));
typedef __bf16 bf16x4 __attribute__((ext_vector_type(4)));
typedef float  f32x4  __attribute__((ext_vector_type(4)));

#define NB 8
#define NC 64
#define NH 256
#define NW 256
#define LDSW 258   // w = -1..256 -> row r = w+1; rows 0 and 257 stay zero
#define LDSC 72    // ci stride (pad 64->72): rows are 144 B, 16B-aligned

// tanh(x) = 1 - 2/(1+e^{2x}); e=Inf -> +1, e=0 -> -1; branch-free, NaN-free
__device__ __forceinline__ float fast_tanh(float x) {
    float e = __expf(2.0f * x);
    return 1.0f - 2.0f / (1.0f + e);
}

// One WG per batch; the whole H-recurrence for batch b runs in this WG.
// Inputs/outputs are fp32 (per reference); conv runs on bf16 MFMA with fp32
// accumulate; the LDS-carried previous row is bf16.
__global__ __launch_bounds__(512, 1)
void spconv_batch(const float* __restrict__ Xg,
                  const float* __restrict__ Wg,
                  const float* __restrict__ Bg,
                  float* __restrict__ Yg)
{
    const int b    = blockIdx.x;
    const int tid  = threadIdx.x;
    const int wv   = tid >> 6;     // 0..7
    const int lane = tid & 63;
    const int g    = lane >> 4;    // quad
    const int lm   = lane & 15;

    __shared__ __bf16 buf[LDSW][LDSC];   // prev row Y[h-1], layout [w+1][ci]

    // ---- zero ALL of LDS, then barrier before anyone writes h=0 data ----
    for (int i = tid; i < LDSW * LDSC; i += 512)
        ((__bf16*)buf)[i] = (__bf16)0.0f;
    __syncthreads();

    // ---- A fragments (weights), all 4 co-tiles, resident in VGPRs ----
    // chunk c: k-tap = c>>1, ci0 = 32*(c&1)+8g;  A[m=lm][q=8g+j] = W[co][ci0+j][k]
    bf16x8 afrag[4][6];
    #pragma unroll
    for (int ct = 0; ct < 4; ++ct) {
        const int co = ct * 16 + lm;
        #pragma unroll
        for (int c = 0; c < 6; ++c) {
            const int k = c >> 1, ci0 = 32 * (c & 1) + 8 * g;
            bf16x8 a;
            #pragma unroll
            for (int j = 0; j < 8; ++j)
                a[j] = (__bf16)Wg[(co * NC + (ci0 + j)) * 3 + k];
            afrag[ct][c] = a;
        }
    }

    // C/D layout: lane holds rows co = ct*16 + 4g + i, col w = w0 + lm
    float bias_r[4][4];
    #pragma unroll
    for (int ct = 0; ct < 4; ++ct)
        #pragma unroll
        for (int i = 0; i < 4; ++i)
            bias_r[ct][i] = Bg[ct * 16 + 4 * g + i];

    // ---- h = 0: exact fp32 passthrough; bf16 copy into LDS ----
    #pragma unroll
    for (int t2 = 0; t2 < 2; ++t2) {
        const int w0 = (wv + 8 * t2) * 16;
        #pragma unroll
        for (int ct = 0; ct < 4; ++ct) {
            bf16x4 pk;
            #pragma unroll
            for (int i = 0; i < 4; ++i) {
                const int co = ct * 16 + 4 * g + i;
                const size_t idx = ((size_t)(b * NC + co) * NH + 0) * NW + w0 + lm;
                float v = Xg[idx];
                Yg[idx] = v;
                pk[i] = (__bf16)v;
            }
            *(bf16x4*)&buf[w0 + lm + 1][ct * 16 + 4 * g] = pk;
        }
    }
    __syncthreads();

    for (int h = 1; h < NH; ++h) {
        __bf16 yv[2][4][4];
        #pragma unroll
        for (int t2 = 0; t2 < 2; ++t2) {
            const int w0 = (wv + 8 * t2) * 16;
            // B fragments: B[q=8g+j][n=lm] = Yprev[ci0+j][w0+lm-1+k] -> row w0+lm+k
            bf16x8 bfr[6];
            #pragma unroll
            for (int c = 0; c < 6; ++c)
                bfr[c] = *(const bf16x8*)&buf[w0 + lm + (c >> 1)][32 * (c & 1) + 8 * g];
            #pragma unroll
            for (int ct = 0; ct < 4; ++ct) {
                f32x4 acc = {0.f, 0.f, 0.f, 0.f};
                #pragma unroll
                for (int c = 0; c < 6; ++c)
                    acc = __builtin_amdgcn_mfma_f32_16x16x32_bf16(afrag[ct][c], bfr[c],
                                                                  acc, 0, 0, 0);
                #pragma unroll
                for (int i = 0; i < 4; ++i) {
                    const int co = ct * 16 + 4 * g + i;
                    const size_t idx = ((size_t)(b * NC + co) * NH + h) * NW + w0 + lm;
                    float v = Xg[idx] + fast_tanh(acc[i] + bias_r[ct][i]);
                    Yg[idx] = v;               // fp32 output
                    yv[t2][ct][i] = (__bf16)v; // bf16 carry for next step
                }
            }
        }
        __syncthreads();   // all prev-row LDS reads complete
        #pragma unroll
        for (int t2 = 0; t2 < 2; ++t2) {
            const int w0 = (wv + 8 * t2) * 16;
            #pragma unroll
            for (int ct = 0; ct < 4; ++ct) {
                bf16x4 pk;
                #pragma unroll
                for (int i = 0; i < 4; ++i) pk[i] = yv[t2][ct][i];
                *(bf16x4*)&buf[w0 + lm + 1][ct * 16 + 4 * g] = pk;
            }
        }
        __syncthreads();   // new row visible before next step's reads
    }
}

extern "C" void kernel_launch(void* const* d_in, const int* in_sizes, int n_in,
                              void* d_out, int out_size, void* d_ws, size_t ws_size,
                              hipStream_t stream)
{
    const float* X  = (const float*)d_in[0];
    const float* Wc = (const float*)d_in[1];
    const float* Bc = (const float*)d_in[2];
    float* Y        = (float*)d_out;

    hipLaunchKernelGGL(spconv_batch, dim3(NB), dim3(512), 0, stream, X, Wc, Bc, Y);
}

// Round 4
// 779.927 us; speedup vs baseline: 1.4920x; 1.4920x over previous
//
#include <hip/hip_runtime.h>
#include <hip/hip_bf16.h>

typedef __bf16 bf16x8 __attribute__((ext_vector_type(8)));
typedef __bf16 bf16x4 __attribute__((ext_vector_type(4)));
typedef float  f32x4  __attribute__((ext_vector_type(4)));

#define NB 8
#define NC 64
#define NH 256
#define NW 256
#define NT 16     // W tiles
#define WT 16     // core width per WG
#define SEG 16    // steps between neighbor syncs
#define CW 48     // computed window width (core + 16 halo each side)
#define LDSW 50   // window + conv pad columns, w = wc0-1 .. wc0+48
#define LDSC 72   // ci stride: 144 B rows keep ds_read_b128 16B-aligned

// tanh(x) = 1 - 2/(1+e^{2x}); bounded, branch-free, NaN-free for finite x
__device__ __forceinline__ float fast_tanh(float x) {
    float e = __expf(2.0f * x);
    return 1.0f - 2.0f / (1.0f + e);
}

// 128 WGs = 8 batches x 16 W-tiles; blockIdx&7 = batch -> same-batch tiles
// share an XCD (perf heuristic only; agent-scope sync gives correctness).
// Each WG computes a 48-wide trapezoid window; neighbor halo exchange through
// global Y only every SEG steps.
__global__ __launch_bounds__(256, 1)
void spconv_trap(const float* __restrict__ Xg,
                 const float* __restrict__ Wg,
                 const float* __restrict__ Bg,
                 float* __restrict__ Yg,
                 int* __restrict__ flags)
{
    const int b    = blockIdx.x & 7;
    const int t    = blockIdx.x >> 3;
    const int tid  = threadIdx.x;
    const int wv   = tid >> 6;     // 0..3: wave = co-tile
    const int lane = tid & 63;
    const int g    = lane >> 4;    // quad
    const int lm   = lane & 15;
    const int w0   = t * WT;
    const int wc0  = w0 - WT;      // window start

    __shared__ __bf16 buf[LDSW][LDSC];  // prev row, [w - wc0 + 1][ci]

    // ---- A fragments (this wave's co-tile only), resident in VGPRs ----
    // chunk c: k-tap = c>>1, ci0 = 32*(c&1)+8g; A[m=lm][q=8g+j]=W[co][ci0+j][k]
    bf16x8 afrag[6];
    {
        const int co = wv * 16 + lm;
        #pragma unroll
        for (int c = 0; c < 6; ++c) {
            const int k = c >> 1, ci0 = 32 * (c & 1) + 8 * g;
            bf16x8 a;
            #pragma unroll
            for (int j = 0; j < 8; ++j)
                a[j] = (__bf16)Wg[(co * NC + ci0 + j) * 3 + k];
            afrag[c] = a;
        }
    }
    float bias_r[4];
    #pragma unroll
    for (int i = 0; i < 4; ++i)
        bias_r[i] = Bg[wv * 16 + 4 * g + i];

    // ---- init: LDS <- X row 0 over the full window (clamped to 0 outside) ----
    {
        const int ci = tid & 63;
        for (int r = (tid >> 6); r < LDSW; r += 4) {
            const int w = wc0 - 1 + r;
            float v = (w >= 0 && w < NW)
                    ? Xg[((size_t)(b * NC + ci) * NH + 0) * NW + w] : 0.0f;
            buf[r][ci] = (__bf16)v;
        }
    }
    // Y row 0 = X row 0 (exact fp32 passthrough), core columns only
    #pragma unroll
    for (int i = 0; i < 4; ++i) {
        const int co = wv * 16 + 4 * g + i;
        const size_t idx = ((size_t)(b * NC + co) * NH + 0) * NW + w0 + lm;
        Yg[idx] = Xg[idx];
    }

    // per-lane window columns and validity (fixed for the whole kernel)
    bool wok[3];
    #pragma unroll
    for (int s = 0; s < 3; ++s) {
        const int w = wc0 + 16 * s + lm;
        wok[s] = (w >= 0 && w < NW);
    }

    // prefetch X row 1
    float xcur[3][4], xnext[3][4];
    #pragma unroll
    for (int s = 0; s < 3; ++s)
        #pragma unroll
        for (int i = 0; i < 4; ++i) {
            const int co = wv * 16 + 4 * g + i;
            const int w  = wc0 + 16 * s + lm;
            xcur[s][i] = wok[s]
                ? Xg[((size_t)(b * NC + co) * NH + 1) * NW + w] : 0.0f;
        }
    __syncthreads();

    const int myflag = b * NT + t;

    for (int h = 1; h < NH; ++h) {
        // ---- prefetch X[h+1] (independent of recurrence; hides latency) ----
        if (h + 1 < NH) {
            #pragma unroll
            for (int s = 0; s < 3; ++s)
                #pragma unroll
                for (int i = 0; i < 4; ++i) {
                    const int co = wv * 16 + 4 * g + i;
                    const int w  = wc0 + 16 * s + lm;
                    xnext[s][i] = wok[s]
                        ? Xg[((size_t)(b * NC + co) * NH + h + 1) * NW + w] : 0.0f;
                }
        }

        // ---- conv over 3 w-subtiles: D = sum_c A_c * B_c, K = 192 ----
        float yv[3][4];
        #pragma unroll
        for (int s = 0; s < 3; ++s) {
            f32x4 acc = {0.f, 0.f, 0.f, 0.f};
            #pragma unroll
            for (int c = 0; c < 6; ++c) {
                const bf16x8 bfr =
                    *(const bf16x8*)&buf[16 * s + lm + (c >> 1)][32 * (c & 1) + 8 * g];
                acc = __builtin_amdgcn_mfma_f32_16x16x32_bf16(afrag[c], bfr, acc, 0, 0, 0);
            }
            #pragma unroll
            for (int i = 0; i < 4; ++i)
                yv[s][i] = xcur[s][i] + fast_tanh(acc[i] + bias_r[i]);
        }
        // ---- store core columns (s = 1) to global, fp32 ----
        #pragma unroll
        for (int i = 0; i < 4; ++i) {
            const int co = wv * 16 + 4 * g + i;
            Yg[((size_t)(b * NC + co) * NH + h) * NW + w0 + lm] = yv[1][i];
        }

        __syncthreads();   // all prev-row LDS reads complete

        // ---- write new row into LDS (cells outside [0,NW) pinned to 0) ----
        #pragma unroll
        for (int s = 0; s < 3; ++s) {
            bf16x4 pk;
            #pragma unroll
            for (int i = 0; i < 4; ++i)
                pk[i] = wok[s] ? (__bf16)yv[s][i] : (__bf16)0.0f;
            *(bf16x4*)&buf[16 * s + lm + 1][wv * 16 + 4 * g] = pk;
        }

        const bool boundary = (h < NH - 1) && ((h & (SEG - 1)) == 0);
        if (boundary) {
            const int k = h >> 4;          // completed segment index, 1..15
            __threadfence();               // publish my Y stores at agent scope
            __syncthreads();               // all fences done before flag store
            if (tid == 0)
                __hip_atomic_store(&flags[myflag], k,
                                   __ATOMIC_RELEASE, __HIP_MEMORY_SCOPE_AGENT);
            // spin in two different waves so the waits overlap
            if (t > 0 && tid == 32) {
                while (__hip_atomic_load(&flags[myflag - 1], __ATOMIC_ACQUIRE,
                                         __HIP_MEMORY_SCOPE_AGENT) < k)
                    __builtin_amdgcn_s_sleep(2);
            }
            if (t < NT - 1 && tid == 96) {
                while (__hip_atomic_load(&flags[myflag + 1], __ATOMIC_ACQUIRE,
                                         __HIP_MEMORY_SCOPE_AGENT) < k)
                    __builtin_amdgcn_s_sleep(2);
            }
            __syncthreads();
            // refill halo regions (rows 1..16 and 33..48) from neighbors' Y[h]
            for (int idx = tid; idx < 2048; idx += 256) {
                const int wloc = idx & 15;
                const int ci   = (idx >> 4) & 63;
                const int side = idx >> 10;            // 0 = left, 1 = right
                const bool have = side ? (t < NT - 1) : (t > 0);
                if (have) {
                    const int w = w0 - 16 + wloc + side * 32;
                    const int r = side * 32 + wloc + 1;
                    buf[r][ci] =
                        (__bf16)Yg[((size_t)(b * NC + ci) * NH + h) * NW + w];
                }
            }
            __syncthreads();
        } else {
            __syncthreads();   // new row visible before next step's reads
        }

        #pragma unroll
        for (int s = 0; s < 3; ++s)
            #pragma unroll
            for (int i = 0; i < 4; ++i)
                xcur[s][i] = xnext[s][i];
    }
}

extern "C" void kernel_launch(void* const* d_in, const int* in_sizes, int n_in,
                              void* d_out, int out_size, void* d_ws, size_t ws_size,
                              hipStream_t stream)
{
    const float* X  = (const float*)d_in[0];
    const float* Wc = (const float*)d_in[1];
    const float* Bc = (const float*)d_in[2];
    float* Y        = (float*)d_out;
    int* flags      = (int*)d_ws;   // 128 ints; d_ws is poisoned 0xAA -> memset

    hipMemsetAsync(d_ws, 0, NB * NT * sizeof(int), stream);

    dim3 grid(NB * NT);   // 128 WGs x 4 waves: all co-resident, spin-safe
    dim3 block(256);
    hipLaunchKernelGGL(spconv_trap, grid, block, 0, stream, X, Wc, Bc, Y, flags);
}